// Round 4
// baseline (454.219 us; speedup 1.0000x reference)
//
#include <hip/hip_runtime.h>
#include <hip/hip_bf16.h>
#include <hip/hip_cooperative_groups.h>
#include <math.h>

namespace cg = cooperative_groups;

// Problem: B=8, C=512, H=W=64 -> HW=4096, Td=512. KV len = 1 -> softmax == 1
// -> attention out == v broadcast; rgb_t/dep_t are per-(b,c) constants.
// Only losses read the big tensors; fused output is a per-(b,c) broadcast.
//
// R1: no same-line device atomics (150us XCD ping-pong). R2: nontemporal
// builtins need ext_vector types. R3: 6 launches -> 2 (cooperative chain).

#define BB 8
#define CC 512
#define TOTAL (8 * 512 * 4096)   // 16777216
#define N4 (TOTAL / 4)           // 4194304 float4s
#define LOSS_BLOCKS 1024
#define CHAIN_BLOCKS 512

typedef float f32x4 __attribute__((ext_vector_type(4)));

// ---------------- Launch 1: loss partials (independent of gate chain) ------
__global__ __launch_bounds__(256) void k_loss(
    const f32x4* __restrict__ rgb, const f32x4* __restrict__ dep,
    float* __restrict__ partials)   // [1024] ssq | [1024] sab
{
    const int stride = gridDim.x * blockDim.x;
    float ssq = 0.0f, sab = 0.0f;
    for (int j = blockIdx.x * blockDim.x + threadIdx.x; j < N4; j += stride) {
        f32x4 a = __builtin_nontemporal_load(&rgb[j]);
        f32x4 b = __builtin_nontemporal_load(&dep[j]);
        float d0 = a.x - b.x, d1 = a.y - b.y, d2 = a.z - b.z, d3 = a.w - b.w;
        ssq += d0 * d0 + d1 * d1 + d2 * d2 + d3 * d3;
        sab += fabsf(d0) + fabsf(d1) + fabsf(d2) + fabsf(d3);
    }
    #pragma unroll
    for (int off = 32; off > 0; off >>= 1) {
        ssq += __shfl_xor(ssq, off, 64);
        sab += __shfl_xor(sab, off, 64);
    }
    __shared__ float ls[8];
    const int lane = threadIdx.x & 63;
    const int wv   = threadIdx.x >> 6;
    if (lane == 0) { ls[wv] = ssq; ls[4 + wv] = sab; }
    __syncthreads();
    if (threadIdx.x == 0) {
        partials[blockIdx.x]               = ls[0] + ls[1] + ls[2] + ls[3];
        partials[LOSS_BLOCKS + blockIdx.x] = ls[4] + ls[5] + ls[6] + ls[7];
    }
}

// Batched mat-vec for one output column o across all 8 batches, one wave.
// acc[b] = W_row . x[b] ; K multiple of 256, rows 16B-aligned.
__device__ __forceinline__ void mv8(
    const float* __restrict__ Wrow, const float* __restrict__ x, int ldx,
    int K, int lane, float* acc)
{
    #pragma unroll
    for (int b = 0; b < BB; ++b) acc[b] = 0.0f;
    const f32x4* W4 = (const f32x4*)Wrow;
    const int K4 = K >> 2;
    for (int t = lane; t < K4; t += 64) {
        f32x4 w = W4[t];
        #pragma unroll
        for (int b = 0; b < BB; ++b) {
            f32x4 xv = ((const f32x4*)(x + b * ldx))[t];
            acc[b] += w.x * xv.x + w.y * xv.y + w.z * xv.z + w.w * xv.w;
        }
    }
    #pragma unroll
    for (int off = 32; off > 0; off >>= 1) {
        #pragma unroll
        for (int b = 0; b < BB; ++b)
            acc[b] += __shfl_xor(acc[b], off, 64);
    }
}

// ---------------- Launch 2: cooperative chain + broadcast ------------------
// 512 blocks x 256 thr. Waves 0..511 (blocks 0..127) run the 4 chain stages
// (one output column per wave); block 511 reduces loss partials during
// stage 1; after the last sync ALL 512 blocks do the 67MB broadcast store.
__global__ __launch_bounds__(256) void k_chain(
    const float* __restrict__ text,
    const float* __restrict__ tp_w,  const float* __restrict__ tp_b,
    const float* __restrict__ rwqkv, const float* __restrict__ rbqkv,
    const float* __restrict__ rwo,   const float* __restrict__ rbo,
    const float* __restrict__ dwqkv, const float* __restrict__ dbqkv,
    const float* __restrict__ dwo,   const float* __restrict__ dbo,
    const float* __restrict__ gw,    const float* __restrict__ gb,
    const float* __restrict__ bng,   const float* __restrict__ bnb,
    float* __restrict__ tp, float* __restrict__ vr, float* __restrict__ vd,
    float* __restrict__ rd, float* __restrict__ fv,
    const float* __restrict__ partials, float* __restrict__ out_sc,
    f32x4* __restrict__ out)
{
    cg::grid_group grid = cg::this_grid();
    const int lane = threadIdx.x & 63;
    const int w    = (blockIdx.x << 2) + (threadIdx.x >> 6);  // 0..2047
    float acc[BB];
    __shared__ float ls[8];

    // ---- Stage 1: tp[b, o] = tp_w[o,:] . text[b,:] + tp_b[o]
    if (w < 512) {
        mv8(tp_w + (size_t)w * 512, text, 512, 512, lane, acc);
        if (lane == 0) {
            float bs = tp_b[w];
            #pragma unroll
            for (int b = 0; b < BB; ++b) tp[b * 512 + w] = acc[b] + bs;
        }
    } else if (blockIdx.x == CHAIN_BLOCKS - 1) {
        // reduce loss partials (k_loss finished before us: stream order)
        float ssq = 0.0f, sab = 0.0f;
        for (int i = threadIdx.x; i < LOSS_BLOCKS; i += 256) {
            ssq += partials[i];
            sab += partials[LOSS_BLOCKS + i];
        }
        #pragma unroll
        for (int off = 32; off > 0; off >>= 1) {
            ssq += __shfl_xor(ssq, off, 64);
            sab += __shfl_xor(sab, off, 64);
        }
        const int wv = threadIdx.x >> 6;
        if (lane == 0) { ls[wv] = ssq; ls[4 + wv] = sab; }
        __syncthreads();
        if (threadIdx.x == 0) {
            const float invN = 1.0f / (float)TOTAL;
            out_sc[0] = (ls[0] + ls[1] + ls[2] + ls[3]) * invN;
            out_sc[1] = (ls[4] + ls[5] + ls[6] + ls[7]) * invN;
        }
    }
    grid.sync();

    // ---- Stage 2: v = Wv . tp + bv for rgb & dep (Wv = Wqkv rows [2C,3C))
    if (w < 512) {
        mv8(rwqkv + (size_t)(1024 + w) * 512, tp, 512, 512, lane, acc);
        if (lane == 0) {
            float bs = rbqkv[1024 + w];
            #pragma unroll
            for (int b = 0; b < BB; ++b) vr[b * 512 + w] = acc[b] + bs;
        }
        mv8(dwqkv + (size_t)(1024 + w) * 512, tp, 512, 512, lane, acc);
        if (lane == 0) {
            float bs = dbqkv[1024 + w];
            #pragma unroll
            for (int b = 0; b < BB; ++b) vd[b * 512 + w] = acc[b] + bs;
        }
    }
    grid.sync();

    // ---- Stage 3: r = Wo . v + bo -> rd[:, :512] (rgb), rd[:, 512:] (dep)
    if (w < 512) {
        mv8(rwo + (size_t)w * 512, vr, 512, 512, lane, acc);
        if (lane == 0) {
            float bs = rbo[w];
            #pragma unroll
            for (int b = 0; b < BB; ++b) rd[b * 1024 + w] = acc[b] + bs;
        }
        mv8(dwo + (size_t)w * 512, vd, 512, 512, lane, acc);
        if (lane == 0) {
            float bs = dbo[w];
            #pragma unroll
            for (int b = 0; b < BB; ++b) rd[b * 1024 + 512 + w] = acc[b] + bs;
        }
    }
    grid.sync();

    // ---- Stage 4: pre = gw . rd + gb; BN over batch (spatially constant =>
    // stats over 8 batch values == reference stats over (B,H,W)); sigmoid;
    // fv = g*r + (1-g)*d
    if (w < 512) {
        mv8(gw + (size_t)w * 1024, rd, 1024, 1024, lane, acc);
        if (lane == 0) {
            float bsv = gb[w];
            float pre[BB];
            float mean = 0.0f;
            #pragma unroll
            for (int b = 0; b < BB; ++b) { pre[b] = acc[b] + bsv; mean += pre[b]; }
            mean *= 0.125f;
            float var = 0.0f;
            #pragma unroll
            for (int b = 0; b < BB; ++b) { float dv = pre[b] - mean; var += dv * dv; }
            var *= 0.125f;
            float inv = rsqrtf(var + 1e-5f);
            float g = bng[w], bb2 = bnb[w];
            #pragma unroll
            for (int b = 0; b < BB; ++b) {
                float xh = (pre[b] - mean) * inv;
                float z  = g * xh + bb2;
                float gt = 1.0f / (1.0f + expf(-z));
                float rv = rd[b * 1024 + w];
                float dv = rd[b * 1024 + 512 + w];
                fv[b * CC + w] = gt * rv + (1.0f - gt) * dv;
            }
        }
    }
    grid.sync();

    // ---- Stage 5: broadcast fv over (H,W): out[j] = fv[j>>10], all blocks
    const int stride = gridDim.x * blockDim.x;   // 131072
    for (int j = blockIdx.x * blockDim.x + threadIdx.x; j < N4; j += stride) {
        float f = fv[j >> 10];
        f32x4 v = {f, f, f, f};
        __builtin_nontemporal_store(v, &out[j]);
    }
}

extern "C" void kernel_launch(void* const* d_in, const int* in_sizes, int n_in,
                              void* d_out, int out_size, void* d_ws, size_t ws_size,
                              hipStream_t stream) {
    const float* rgb   = (const float*)d_in[0];
    const float* dep   = (const float*)d_in[1];
    const float* text  = (const float*)d_in[2];
    const float* tp_w  = (const float*)d_in[3];
    const float* tp_b  = (const float*)d_in[4];
    const float* rwqkv = (const float*)d_in[5];
    const float* rbqkv = (const float*)d_in[6];
    const float* rwo   = (const float*)d_in[7];
    const float* rbo   = (const float*)d_in[8];
    const float* dwqkv = (const float*)d_in[9];
    const float* dbqkv = (const float*)d_in[10];
    const float* dwo   = (const float*)d_in[11];
    const float* dbo   = (const float*)d_in[12];
    const float* gw    = (const float*)d_in[13];
    const float* gb    = (const float*)d_in[14];
    const float* bng   = (const float*)d_in[15];
    const float* bnb   = (const float*)d_in[16];

    float* ws  = (float*)d_ws;
    float* tp  = ws;              // 4096
    float* vr  = ws + 4096;       // 4096
    float* vd  = ws + 8192;       // 4096
    float* rd  = ws + 12288;      // 8192
    float* fv  = ws + 20480;      // 4096
    float* partials = ws + 24576; // 2048

    float* outf   = (float*)d_out;
    float* out_sc = outf + TOTAL;

    // Launch 1: loss partials (independent of the gate chain)
    k_loss<<<LOSS_BLOCKS, 256, 0, stream>>>(
        (const f32x4*)rgb, (const f32x4*)dep, partials);

    // Launch 2: cooperative chain + partial-finalize + broadcast
    void* args[] = {
        (void*)&text,
        (void*)&tp_w,  (void*)&tp_b,
        (void*)&rwqkv, (void*)&rbqkv, (void*)&rwo, (void*)&rbo,
        (void*)&dwqkv, (void*)&dbqkv, (void*)&dwo, (void*)&dbo,
        (void*)&gw,    (void*)&gb,    (void*)&bng, (void*)&bnb,
        (void*)&tp, (void*)&vr, (void*)&vd, (void*)&rd, (void*)&fv,
        (void*)&partials, (void*)&out_sc,
        (void*)&outf   // f32x4* out (same address)
    };
    hipLaunchCooperativeKernel((void*)k_chain, dim3(CHAIN_BLOCKS), dim3(256),
                               args, 0, stream);
}

// Round 5
// 213.329 us; speedup vs baseline: 2.1292x; 2.1292x over previous
//
#include <hip/hip_runtime.h>
#include <hip/hip_bf16.h>
#include <math.h>

// Problem: B=8, C=512, H=W=64 -> HW=4096, Td=512. KV len = 1 -> softmax == 1
// -> attention out == v broadcast; rgb_t/dep_t are per-(b,c) constants.
// Only the losses read the big tensors; fused output is a per-(b,c) broadcast.
//
// R1: no same-line device atomics (150us XCD ping-pong).
// R2: nontemporal builtins need ext_vector types.
// R4: cooperative grid.sync is ~50us/sync on gfx950 -- never again.
// R5 structure: loss read (134MB) chunked INTO the 3 chain-stage launches as
// extra blocks; gate stage absorbs the 67MB broadcast write (4x redundant
// tiny matvec per spatial quarter). 5 launches, all BW-busy.

#define BB 8
#define CC 512
#define TOTAL (8 * 512 * 4096)   // 16777216
#define N4 (TOTAL / 4)           // 4194304 f32x4
#define Q4 (N4 / 4)              // 1048576 per loss chunk
#define CHAINB 128               // chain blocks per stage launch
#define LOSSB_A 896              // loss blocks in each k_stage launch
#define LOSSB_B 512              // loss blocks in k_gate_bcast
#define NPART 3200               // 3*896 + 512 partial slots per loss type

typedef float f32x4 __attribute__((ext_vector_type(4)));

// Batched mat-vec: acc[b] = W_row . x[b]  (K multiple of 256, 16B-aligned).
// Butterfly reduction leaves the FULL total in ALL 64 lanes.
__device__ __forceinline__ void mv8(
    const float* __restrict__ Wrow, const float* __restrict__ x, int ldx,
    int K, int lane, float* acc)
{
    #pragma unroll
    for (int b = 0; b < BB; ++b) acc[b] = 0.0f;
    const f32x4* W4 = (const f32x4*)Wrow;
    const int K4 = K >> 2;
    for (int t = lane; t < K4; t += 64) {
        f32x4 w = W4[t];
        #pragma unroll
        for (int b = 0; b < BB; ++b) {
            f32x4 xv = ((const f32x4*)(x + b * ldx))[t];
            acc[b] += w.x * xv.x + w.y * xv.y + w.z * xv.z + w.w * xv.w;
        }
    }
    #pragma unroll
    for (int off = 32; off > 0; off >>= 1) {
        #pragma unroll
        for (int b = 0; b < BB; ++b)
            acc[b] += __shfl_xor(acc[b], off, 64);
    }
}

// Loss partial over f32x4 range [start, start+Q4), written to slot `pidx`.
__device__ __forceinline__ void loss_chunk(
    const f32x4* __restrict__ rgb, const f32x4* __restrict__ dep,
    int start, int nblocks, int lid, float* __restrict__ partials, int pidx)
{
    const int stride = nblocks * 256;
    float ssq = 0.0f, sab = 0.0f;
    for (int j = start + lid * 256 + threadIdx.x; j < start + Q4; j += stride) {
        f32x4 a = __builtin_nontemporal_load(&rgb[j]);
        f32x4 b = __builtin_nontemporal_load(&dep[j]);
        float d0 = a.x - b.x, d1 = a.y - b.y, d2 = a.z - b.z, d3 = a.w - b.w;
        ssq += d0 * d0 + d1 * d1 + d2 * d2 + d3 * d3;
        sab += fabsf(d0) + fabsf(d1) + fabsf(d2) + fabsf(d3);
    }
    #pragma unroll
    for (int off = 32; off > 0; off >>= 1) {
        ssq += __shfl_xor(ssq, off, 64);
        sab += __shfl_xor(sab, off, 64);
    }
    __shared__ float ls[8];
    const int lane = threadIdx.x & 63;
    const int wv   = threadIdx.x >> 6;
    if (lane == 0) { ls[wv] = ssq; ls[4 + wv] = sab; }
    __syncthreads();
    if (threadIdx.x == 0) {
        partials[pidx]         = ls[0] + ls[1] + ls[2] + ls[3];
        partials[4096 + pidx]  = ls[4] + ls[5] + ls[6] + ls[7];
    }
}

// Chain stage (blocks 0..127) + loss chunk `stage-1` (blocks 128..1023).
__global__ __launch_bounds__(256) void k_stage(
    int stage,
    const float* __restrict__ text,
    const float* __restrict__ tp_w,  const float* __restrict__ tp_b,
    const float* __restrict__ rwqkv, const float* __restrict__ rbqkv,
    const float* __restrict__ dwqkv, const float* __restrict__ dbqkv,
    const float* __restrict__ rwo,   const float* __restrict__ rbo,
    const float* __restrict__ dwo,   const float* __restrict__ dbo,
    float* __restrict__ tp, float* __restrict__ vr, float* __restrict__ vd,
    float* __restrict__ rd,
    const f32x4* __restrict__ rgb, const f32x4* __restrict__ dep,
    float* __restrict__ partials)
{
    const int lane = threadIdx.x & 63;
    if (blockIdx.x < CHAINB) {
        const int w = (blockIdx.x << 2) + (threadIdx.x >> 6);  // 0..511
        float acc[BB];
        if (stage == 1) {
            mv8(tp_w + (size_t)w * 512, text, 512, 512, lane, acc);
            if (lane == 0) {
                float bs = tp_b[w];
                #pragma unroll
                for (int b = 0; b < BB; ++b) tp[b * 512 + w] = acc[b] + bs;
            }
        } else if (stage == 2) {
            mv8(rwqkv + (size_t)(1024 + w) * 512, tp, 512, 512, lane, acc);
            if (lane == 0) {
                float bs = rbqkv[1024 + w];
                #pragma unroll
                for (int b = 0; b < BB; ++b) vr[b * 512 + w] = acc[b] + bs;
            }
            mv8(dwqkv + (size_t)(1024 + w) * 512, tp, 512, 512, lane, acc);
            if (lane == 0) {
                float bs = dbqkv[1024 + w];
                #pragma unroll
                for (int b = 0; b < BB; ++b) vd[b * 512 + w] = acc[b] + bs;
            }
        } else {
            mv8(rwo + (size_t)w * 512, vr, 512, 512, lane, acc);
            if (lane == 0) {
                float bs = rbo[w];
                #pragma unroll
                for (int b = 0; b < BB; ++b) rd[b * 1024 + w] = acc[b] + bs;
            }
            mv8(dwo + (size_t)w * 512, vd, 512, 512, lane, acc);
            if (lane == 0) {
                float bs = dbo[w];
                #pragma unroll
                for (int b = 0; b < BB; ++b) rd[b * 1024 + 512 + w] = acc[b] + bs;
            }
        }
    } else {
        const int chunk = stage - 1;                // 0,1,2
        const int lid   = blockIdx.x - CHAINB;      // 0..895
        loss_chunk(rgb, dep, chunk * Q4, LOSSB_A, lid, partials,
                   chunk * LOSSB_A + lid);
    }
}

// Gate + BN(batch) + sigmoid + 67MB broadcast (blocks 0..511, 4x-redundant
// matvec: block = 128 col-groups x 4 spatial quarters) + loss chunk 3
// (blocks 512..1023).
__global__ __launch_bounds__(256) void k_gate_bcast(
    const float* __restrict__ gw,  const float* __restrict__ gb,
    const float* __restrict__ rd,
    const float* __restrict__ bng, const float* __restrict__ bnb,
    const f32x4* __restrict__ rgb, const f32x4* __restrict__ dep,
    f32x4* __restrict__ out, float* __restrict__ partials)
{
    const int lane = threadIdx.x & 63;
    if (blockIdx.x < 512) {
        const int g = blockIdx.x & 127;             // column group
        const int q = blockIdx.x >> 7;              // spatial quarter
        const int o = (g << 2) + (threadIdx.x >> 6);
        float acc[BB];
        mv8(gw + (size_t)o * 1024, rd, 1024, 1024, lane, acc);
        // all lanes hold the full sums -> every lane computes fv identically
        float bsv = gb[o];
        float pre[BB];
        float mean = 0.0f;
        #pragma unroll
        for (int b = 0; b < BB; ++b) { pre[b] = acc[b] + bsv; mean += pre[b]; }
        mean *= 0.125f;
        float var = 0.0f;
        #pragma unroll
        for (int b = 0; b < BB; ++b) { float dv = pre[b] - mean; var += dv * dv; }
        var *= 0.125f;
        float inv = rsqrtf(var + 1e-5f);
        float gg = bng[o], bb2 = bnb[o];
        #pragma unroll
        for (int b = 0; b < BB; ++b) {
            float xh = (pre[b] - mean) * inv;
            float z  = gg * xh + bb2;
            float gt = 1.0f / (1.0f + expf(-z));
            float rv = rd[b * 1024 + o];
            float dv = rd[b * 1024 + 512 + o];
            float f  = gt * rv + (1.0f - gt) * dv;
            f32x4 v  = {f, f, f, f};
            // f32x4 base: b*(512*4096/4) + o*(4096/4) + q*(1024/4)
            const int base = b * 524288 + o * 1024 + q * 256;
            #pragma unroll
            for (int i = 0; i < 4; ++i)
                __builtin_nontemporal_store(v, &out[base + i * 64 + lane]);
        }
    } else {
        const int lid = blockIdx.x - 512;           // 0..511
        loss_chunk(rgb, dep, 3 * Q4, LOSSB_B, lid, partials,
                   3 * LOSSB_A + lid);
    }
}

// Reduce NPART partials per loss -> two scalars.
__global__ __launch_bounds__(256) void k_final(
    const float* __restrict__ partials, float* __restrict__ out_sc)
{
    float ssq = 0.0f, sab = 0.0f;
    for (int i = threadIdx.x; i < NPART; i += 256) {
        ssq += partials[i];
        sab += partials[4096 + i];
    }
    #pragma unroll
    for (int off = 32; off > 0; off >>= 1) {
        ssq += __shfl_xor(ssq, off, 64);
        sab += __shfl_xor(sab, off, 64);
    }
    __shared__ float ls[8];
    const int lane = threadIdx.x & 63;
    const int wv   = threadIdx.x >> 6;
    if (lane == 0) { ls[wv] = ssq; ls[4 + wv] = sab; }
    __syncthreads();
    if (threadIdx.x == 0) {
        const float invN = 1.0f / (float)TOTAL;
        out_sc[0] = (ls[0] + ls[1] + ls[2] + ls[3]) * invN;
        out_sc[1] = (ls[4] + ls[5] + ls[6] + ls[7]) * invN;
    }
}

extern "C" void kernel_launch(void* const* d_in, const int* in_sizes, int n_in,
                              void* d_out, int out_size, void* d_ws, size_t ws_size,
                              hipStream_t stream) {
    const float* rgb   = (const float*)d_in[0];
    const float* dep   = (const float*)d_in[1];
    const float* text  = (const float*)d_in[2];
    const float* tp_w  = (const float*)d_in[3];
    const float* tp_b  = (const float*)d_in[4];
    const float* rwqkv = (const float*)d_in[5];
    const float* rbqkv = (const float*)d_in[6];
    const float* rwo   = (const float*)d_in[7];
    const float* rbo   = (const float*)d_in[8];
    const float* dwqkv = (const float*)d_in[9];
    const float* dbqkv = (const float*)d_in[10];
    const float* dwo   = (const float*)d_in[11];
    const float* dbo   = (const float*)d_in[12];
    const float* gw    = (const float*)d_in[13];
    const float* gb    = (const float*)d_in[14];
    const float* bng   = (const float*)d_in[15];
    const float* bnb   = (const float*)d_in[16];

    float* ws  = (float*)d_ws;
    float* tp  = ws;              // 4096
    float* vr  = ws + 4096;       // 4096
    float* vd  = ws + 8192;       // 4096
    float* rd  = ws + 12288;      // 8192
    float* partials = ws + 20480; // 4096 + NPART (ssq at +0, sab at +4096)

    float* outf   = (float*)d_out;
    float* out_sc = outf + TOTAL;

    const f32x4* rgb4 = (const f32x4*)rgb;
    const f32x4* dep4 = (const f32x4*)dep;

    // Chain stages 1..3, each carrying a quarter of the loss read.
    for (int stage = 1; stage <= 3; ++stage) {
        k_stage<<<CHAINB + LOSSB_A, 256, 0, stream>>>(
            stage, text, tp_w, tp_b, rwqkv, rbqkv, dwqkv, dbqkv,
            rwo, rbo, dwo, dbo, tp, vr, vd, rd, rgb4, dep4, partials);
    }

    // Gate + broadcast + last loss quarter.
    k_gate_bcast<<<512 + LOSSB_B, 256, 0, stream>>>(
        gw, gb, rd, bng, bnb, rgb4, dep4, (f32x4*)outf, partials);

    // Finalize the two scalars.
    k_final<<<1, 256, 0, stream>>>(partials, out_sc);
}